// Round 1
// baseline (329.846 us; speedup 1.0000x reference)
//
#include <hip/hip_runtime.h>
#include <math.h>

// GAT layer, N=8192, F_in=128, F_out=64, fp32.
// Key algebra: e[i][j] = leaky(f1[i]+f2[j]) is piecewise-separable, so
// softmax(e) @ h collapses to prefix sums of exp(f2)*h ordered by f2.
// We use a bucket-histogram CDF (4096 buckets over [-12,12]) instead of a
// sort; boundary-bucket misassignment error ~1e-4 << 6.25e-3 threshold.

constexpr int N    = 8192;
constexpr int FIN  = 128;
constexpr int FOUT = 64;
constexpr int B    = 4096;            // histogram buckets
constexpr float LO = -12.0f;
constexpr float SCALE = (float)B / 24.0f;
constexpr int G    = 64;              // scan chunks
constexpr int CPG  = B / G;           // buckets per chunk = 64
constexpr float NEG_SLOPE = 0.2f;

__device__ __forceinline__ int bucket_of(float x) {
    int b = (int)floorf((x - LO) * SCALE);
    return min(max(b, 0), B - 1);
}

// K1: h = X@W (wave-per-row, W staged in LDS), f1/f2 via butterfly reduce,
// then scatter exp(f2)*h and exp(0.2 f2)*h into bucket histograms.
__global__ __launch_bounds__(256) void k1_h_hist(
    const float* __restrict__ X, const float* __restrict__ W,
    const float* __restrict__ a,
    float* __restrict__ U, float* __restrict__ V,
    float* __restrict__ pu, float* __restrict__ pv,
    float* __restrict__ f1out)
{
    __shared__ float Wl[FIN * FOUT];
    __shared__ float a1l[FOUT], a2l[FOUT];
    int tid = threadIdx.x;
    for (int i = tid; i < FIN * FOUT; i += 256) Wl[i] = W[i];
    if (tid < FOUT) { a1l[tid] = a[tid]; a2l[tid] = a[FOUT + tid]; }
    __syncthreads();

    int wave = tid >> 6, lane = tid & 63;
    int r = blockIdx.x * 4 + wave;
    const float4* xr = (const float4*)(X + (size_t)r * FIN);

    float acc = 0.f;
#pragma unroll
    for (int k4 = 0; k4 < FIN / 4; ++k4) {
        float4 x = xr[k4];
        int k = k4 * 4;
        acc += x.x * Wl[(k + 0) * FOUT + lane];
        acc += x.y * Wl[(k + 1) * FOUT + lane];
        acc += x.z * Wl[(k + 2) * FOUT + lane];
        acc += x.w * Wl[(k + 3) * FOUT + lane];
    }

    float p1 = acc * a1l[lane];
    float p2 = acc * a2l[lane];
#pragma unroll
    for (int off = 32; off > 0; off >>= 1) {
        p1 += __shfl_xor(p1, off);
        p2 += __shfl_xor(p2, off);
    }
    // all 64 lanes now hold full sums
    if (lane == 0) f1out[r] = p1;

    float e2  = expf(p2);
    float e02 = expf(NEG_SLOPE * p2);
    int b = bucket_of(p2);
    atomicAdd(&U[(size_t)b * FOUT + lane], e2  * acc);
    atomicAdd(&V[(size_t)b * FOUT + lane], e02 * acc);
    if (lane == 0) { atomicAdd(&pu[b], e2); atomicAdd(&pv[b], e02); }
}

// K2a: per-chunk column sums (64 chunks x 64 buckets each).
__global__ __launch_bounds__(256) void k2a_partials(
    const float* __restrict__ U, const float* __restrict__ V,
    const float* __restrict__ pu, const float* __restrict__ pv,
    float* __restrict__ partU, float* __restrict__ partV,
    float* __restrict__ partpu, float* __restrict__ partpv)
{
    int g = blockIdx.x;
    int tid = threadIdx.x, lane = tid & 63, wave = tid >> 6;
    __shared__ float su[4][64], sv[4][64];
    float aU = 0.f, aV = 0.f;
#pragma unroll
    for (int m = 0; m < CPG / 4; ++m) {
        int r = g * CPG + wave * (CPG / 4) + m;
        aU += U[(size_t)r * FOUT + lane];
        aV += V[(size_t)r * FOUT + lane];
    }
    su[wave][lane] = aU;
    sv[wave][lane] = aV;
    __syncthreads();
    if (wave == 0) {
        partU[g * 64 + lane] = su[0][lane] + su[1][lane] + su[2][lane] + su[3][lane];
    } else if (wave == 1) {
        partV[g * 64 + lane] = sv[0][lane] + sv[1][lane] + sv[2][lane] + sv[3][lane];
    } else if (wave == 2) {
        float s = pu[g * CPG + lane];
#pragma unroll
        for (int off = 32; off > 0; off >>= 1) s += __shfl_xor(s, off);
        if (lane == 0) partpu[g] = s;
    } else {
        float s = pv[g * CPG + lane];
#pragma unroll
        for (int off = 32; off > 0; off >>= 1) s += __shfl_xor(s, off);
        if (lane == 0) partpv[g] = s;
    }
}

// K2b: exclusive scan of the per-chunk partials (tiny, single block).
__global__ __launch_bounds__(256) void k2b_scan_partials(
    float* __restrict__ partU, float* __restrict__ partV,
    float* __restrict__ partpu, float* __restrict__ partpv)
{
    int tid = threadIdx.x;
    if (tid < 64) {
        float run = 0.f;
        for (int g = 0; g < G; ++g) {
            float t = partU[g * 64 + tid]; partU[g * 64 + tid] = run; run += t;
        }
    } else if (tid < 128) {
        int c = tid - 64;
        float run = 0.f;
        for (int g = 0; g < G; ++g) {
            float t = partV[g * 64 + c]; partV[g * 64 + c] = run; run += t;
        }
    } else if (tid == 128) {
        float run = 0.f;
        for (int g = 0; g < G; ++g) { float t = partpu[g]; partpu[g] = run; run += t; }
    } else if (tid == 129) {
        float run = 0.f;
        for (int g = 0; g < G; ++g) { float t = partpv[g]; partpv[g] = run; run += t; }
    }
}

// K2c: in-place inclusive scan within each chunk, offset by scanned partials.
__global__ __launch_bounds__(256) void k2c_scan_final(
    float* __restrict__ U, float* __restrict__ V,
    float* __restrict__ pu, float* __restrict__ pv,
    const float* __restrict__ partU, const float* __restrict__ partV,
    const float* __restrict__ partpu, const float* __restrict__ partpv)
{
    int g = blockIdx.x;
    int tid = threadIdx.x, lane = tid & 63, wave = tid >> 6;
    if (wave == 0) {
        float run = partU[g * 64 + lane];
#pragma unroll 4
        for (int m = 0; m < CPG; ++m) {
            size_t idx = ((size_t)(g * CPG + m)) * FOUT + lane;
            run += U[idx]; U[idx] = run;
        }
    } else if (wave == 1) {
        float run = partV[g * 64 + lane];
#pragma unroll 4
        for (int m = 0; m < CPG; ++m) {
            size_t idx = ((size_t)(g * CPG + m)) * FOUT + lane;
            run += V[idx]; V[idx] = run;
        }
    } else if (wave == 2) {
        if (lane == 0) {
            float run = partpu[g];
            for (int m = 0; m < CPG; ++m) { int i = g * CPG + m; run += pu[i]; pu[i] = run; }
        } else if (lane == 1) {
            float run = partpv[g];
            for (int m = 0; m < CPG; ++m) { int i = g * CPG + m; run += pv[i]; pv[i] = run; }
        }
    }
}

// K3: per row i, split sums at bucket(-f1[i]), combine two branches, ELU.
__global__ __launch_bounds__(256) void k3_combine(
    const float* __restrict__ f1a,
    const float* __restrict__ U, const float* __restrict__ V,
    const float* __restrict__ pu, const float* __restrict__ pv,
    float* __restrict__ out)
{
    int tid = threadIdx.x, lane = tid & 63, wave = tid >> 6;
    int i = blockIdx.x * 4 + wave;
    float f1 = f1a[i];
    float t = -f1;
    int b = bucket_of(t);
    float A  = expf(f1);
    float Bv = expf(NEG_SLOPE * f1);

    float Utot = U[((size_t)B - 1) * FOUT + lane];
    float putot = pu[B - 1];
    float Upre = 0.f, Vpre = 0.f, pupre = 0.f, pvpre = 0.f;
    if (b > 0) {
        Upre = U[((size_t)b - 1) * FOUT + lane];
        Vpre = V[((size_t)b - 1) * FOUT + lane];
        pupre = pu[b - 1];
        pvpre = pv[b - 1];
    }
    float num = A * (Utot - Upre) + Bv * Vpre;
    float den = A * (putot - pupre) + Bv * pvpre;
    float r = num / den;
    out[(size_t)i * FOUT + lane] = r > 0.f ? r : expm1f(r);
}

extern "C" void kernel_launch(void* const* d_in, const int* in_sizes, int n_in,
                              void* d_out, int out_size, void* d_ws, size_t ws_size,
                              hipStream_t stream)
{
    const float* X = (const float*)d_in[0];
    // d_in[1] = adj_matrix (all-ones, unused by the reference) — never touched.
    const float* W = (const float*)d_in[2];
    const float* a = (const float*)d_in[3];
    float* out = (float*)d_out;

    float* ws = (float*)d_ws;
    float* U      = ws;                          // B*FOUT
    float* V      = U + (size_t)B * FOUT;        // B*FOUT
    float* pu     = V + (size_t)B * FOUT;        // B
    float* pv     = pu + B;                      // B
    float* f1     = pv + B;                      // N
    float* partU  = f1 + N;                      // G*64
    float* partV  = partU + G * 64;              // G*64
    float* partpu = partV + G * 64;              // G
    float* partpv = partpu + G;                  // G

    // zero the histogram region (U,V,pu,pv are contiguous)
    hipMemsetAsync(U, 0, ((size_t)B * FOUT * 2 + 2 * (size_t)B) * sizeof(float), stream);

    k1_h_hist<<<N / 4, 256, 0, stream>>>(X, W, a, U, V, pu, pv, f1);
    k2a_partials<<<G, 256, 0, stream>>>(U, V, pu, pv, partU, partV, partpu, partpv);
    k2b_scan_partials<<<1, 256, 0, stream>>>(partU, partV, partpu, partpv);
    k2c_scan_final<<<G, 256, 0, stream>>>(U, V, pu, pv, partU, partV, partpu, partpv);
    k3_combine<<<N / 4, 256, 0, stream>>>(f1, U, V, pu, pv, out);
}